// Round 7
// baseline (2802.378 us; speedup 1.0000x reference)
//
#include <hip/hip_runtime.h>
#include <hip/hip_bf16.h>
#include <stdint.h>

// x: [B=16, H=224, W=224, C=64] fp32 NHWC; gating_kernel: [2,2,64,1] fp32
// conv stride 2x2 valid -> g: [16,112,112]; top-K=1254 per batch;
// gate = scatter of top-k values; out = x * gate (broadcast 2x2xC).
#define BATCH   16
#define HDIM    224
#define WDIM    224
#define CDIM    64
#define HO      112
#define WO      112
#define NPATCH  (HO * WO)        // 12544 = 256 * 49
#define KSEL    1254
#define ROWF    (WDIM * CDIM)    // 14336 floats per image row
#define PERTHR  49               // keys per thread in select phase
#define ROWF4   (WDIM * 16)      // 3584 float4 per image row
#define BLKROW  14               // 3584 / 256 blocks per row in apply
#define BLKS_PER_BATCH 1568      // conv blocks per batch (12544 patches / 8)

typedef float f32x4 __attribute__((ext_vector_type(4)));

// ---------------------------------------------------------------------------
// Kernel 1 (fused conv + last-block select):
//  conv phase: one patch per half-wave; 2x128 contiguous floats per patch,
//  float4/lane -> 1KB wave loads. 205 MB read, BW-bound (~33 us).
//  Then each block releases its g stores (__threadfence) and bumps a
//  per-batch completion counter; the 1568th block of a batch becomes that
//  batch's selector and runs the R6-proven 32-step bitwise binary search
//  (one-barrier double-buffered counts, stable lowest-index ties) inline.
//  Saves the separate select kernel launch + serialization (~8-10 us).
// ---------------------------------------------------------------------------
__global__ __launch_bounds__(256) void conv_select_kernel(
    const float* __restrict__ x, const float* __restrict__ wk,
    float* __restrict__ g, float* __restrict__ gate,
    unsigned int* __restrict__ counters) {
  const int tid = threadIdx.x;
  const int lane = tid & 31;
  const int p = blockIdx.x * 8 + (tid >> 5);  // 8 half-waves/block

  const int b   = p / NPATCH;                 // uniform per block (12544%8==0)
  const int rem = p - b * NPATCH;
  const int ho  = rem / WO;
  const int wo  = rem - ho * WO;

  const float4 w0 = *reinterpret_cast<const float4*>(wk + lane * 4);
  const float4 w1 = *reinterpret_cast<const float4*>(wk + 128 + lane * 4);

  const long row0 = (long)(b * HDIM + 2 * ho) * ROWF + wo * 128 + lane * 4;
  const float4 a0 = *reinterpret_cast<const float4*>(x + row0);
  const float4 a1 = *reinterpret_cast<const float4*>(x + row0 + ROWF);

  float partial = a0.x * w0.x + a0.y * w0.y + a0.z * w0.z + a0.w * w0.w
                + a1.x * w1.x + a1.y * w1.y + a1.z * w1.z + a1.w * w1.w;

  #pragma unroll
  for (int off = 16; off > 0; off >>= 1)
    partial += __shfl_down(partial, off, 32);

  if (lane == 0) g[p] = partial;

  // ---- completion count: am I the last conv block of this batch? ----
  __shared__ unsigned int sh_prev;
  __threadfence();                 // release: my g stores -> device scope
  __syncthreads();                 // all waves of the block have fenced
  if (tid == 0) sh_prev = atomicAdd(&counters[b], 1u);  // device-scope
  __syncthreads();
  if (sh_prev != BLKS_PER_BATCH - 1) return;   // not the selector
  __threadfence();                 // acquire: other blocks' g stores visible

  // ---- select phase (R6-proven), on batch b ----
  __shared__ int cnt[2][4];
  __shared__ int eq_list[256];
  __shared__ int eq_count;

  const float* __restrict__ gb  = g    + b * NPATCH;
  float* __restrict__       gtb = gate + b * NPATCH;

  uint32_t key[PERTHR];
  #pragma unroll
  for (int j = 0; j < PERTHR; ++j) {
    uint32_t u = __float_as_uint(gb[tid + j * 256]);
    key[j] = (u & 0x80000000u) ? ~u : (u | 0x80000000u);  // monotone map
  }
  if (tid == 0) eq_count = 0;

  int par = 0;
  auto block_count = [&](int c) -> int {   // one barrier per count
    #pragma unroll
    for (int off = 32; off > 0; off >>= 1) c += __shfl_down(c, off, 64);
    if ((tid & 63) == 0) cnt[par][tid >> 6] = c;
    __syncthreads();
    const int tot = cnt[par][0] + cnt[par][1] + cnt[par][2] + cnt[par][3];
    par ^= 1;
    return tot;
  };

  // T = max{t : count(keys >= t) >= K}, built bit by bit from the top.
  uint32_t T = 0;
  for (int bit = 31; bit >= 0; --bit) {
    const uint32_t cand = T | (1u << bit);
    int c = 0;
    #pragma unroll
    for (int j = 0; j < PERTHR; ++j) c += (key[j] >= cand) ? 1 : 0;
    if (block_count(c) >= KSEL) T = cand;   // uniform across block
  }

  int cg = 0;
  #pragma unroll
  for (int j = 0; j < PERTHR; ++j) cg += (key[j] > T) ? 1 : 0;
  const int krem = KSEL - block_count(cg);  // threshold ties to keep

  #pragma unroll
  for (int j = 0; j < PERTHR; ++j) {
    const int i = tid + j * 256;
    const uint32_t k = key[j];
    float v = 0.0f;
    if (k > T) {
      uint32_t u = (k & 0x80000000u) ? (k & 0x7FFFFFFFu) : ~k;
      v = __uint_as_float(u);
    }
    gtb[i] = v;
    if (k == T) {
      int pos = atomicAdd(&eq_count, 1);
      if (pos < 256) eq_list[pos] = i;
    }
  }
  __syncthreads();

  if (tid == 0) {
    const int ec = eq_count;
    const float tval =
        __uint_as_float((T & 0x80000000u) ? (T & 0x7FFFFFFFu) : ~T);
    if (ec <= 256) {
      for (int i = 0; i < ec; ++i) {          // sort tiny tie list by index
        int mn = i;
        for (int j = i + 1; j < ec; ++j)
          if (eq_list[j] < eq_list[mn]) mn = j;
        int t = eq_list[mn]; eq_list[mn] = eq_list[i]; eq_list[i] = t;
      }
      for (int i = 0; i < ec && i < krem; ++i)
        gtb[eq_list[i]] = tval;
    } else {
      int kept = 0;                            // pathological mass-tie path
      for (int i = 0; i < NPATCH && kept < krem; ++i) {
        uint32_t u = __float_as_uint(gb[i]);
        uint32_t k = (u & 0x80000000u) ? ~u : (u | 0x80000000u);
        if (k == T) { gtb[i] = tval; ++kept; }
      }
    }
  }
}

// ---------------------------------------------------------------------------
// Kernel 2: SPARSE apply (unchanged from R4/R6). 90% of patches gate==0 ->
// write zeros without reading x (selected ~20 MB reads, L3-hit).
// Non-temporal stores for the write-once out stream. ~205 MB write floor.
// ---------------------------------------------------------------------------
__global__ __launch_bounds__(256) void apply_gate_kernel(
    const float* __restrict__ x, const float* __restrict__ gate,
    float* __restrict__ out) {
  const int bi = blockIdx.x;
  const int rowblk = bi % BLKROW;
  const int rowid  = bi / BLKROW;          // b*224 + h
  const int h = rowid % HDIM;
  const int b = rowid / HDIM;

  const int v4row = rowblk * 256 + threadIdx.x;
  const int w = v4row >> 4;
  const int gidx = b * NPATCH + (h >> 1) * WO + (w >> 1);

  const float gv = gate[gidx];
  const size_t v4 = (size_t)rowid * ROWF4 + v4row;

  f32x4 o = {0.0f, 0.0f, 0.0f, 0.0f};
  if (gv != 0.0f) {
    const f32x4 a = *reinterpret_cast<const f32x4*>(x + v4 * 4);
    o = a * gv;
  }
  __builtin_nontemporal_store(o, reinterpret_cast<f32x4*>(out + v4 * 4));
}

extern "C" void kernel_launch(void* const* d_in, const int* in_sizes, int n_in,
                              void* d_out, int out_size, void* d_ws, size_t ws_size,
                              hipStream_t stream) {
  const float* x  = (const float*)d_in[0];   // [16,224,224,64]
  const float* wk = (const float*)d_in[1];   // [2,2,64,1]
  float* out = (float*)d_out;

  float* g    = (float*)d_ws;                          // [16, 12544]
  float* gate = g + BATCH * NPATCH;                    // [16, 12544]
  unsigned int* counters = (unsigned int*)(gate + BATCH * NPATCH);  // [16]

  // ws is poisoned 0xAA each call -> counters must be zeroed (async, capturable)
  hipMemsetAsync(counters, 0, BATCH * sizeof(unsigned int), stream);

  conv_select_kernel<<<(BATCH * NPATCH) / 8, 256, 0, stream>>>(
      x, wk, g, gate, counters);
  apply_gate_kernel<<<BATCH * HDIM * BLKROW, 256, 0, stream>>>(x, gate, out);
}

// Round 8
// 354.014 us; speedup vs baseline: 7.9160x; 7.9160x over previous
//
#include <hip/hip_runtime.h>
#include <hip/hip_bf16.h>
#include <stdint.h>

// x: [B=16, H=224, W=224, C=64] fp32 NHWC; gating_kernel: [2,2,64,1] fp32
// conv stride 2x2 valid -> g: [16,112,112]; top-K=1254 per batch;
// gate = scatter of top-k values; out = x * gate (broadcast 2x2xC).
//
// R8 = exact revert to the proven R6 three-kernel structure (353.3 us).
// R7's fused conv+select (last-block pattern) was a 7x regression: one
// device-scope __threadfence per block x 25088 blocks serialized the chip
// (41 GB/s, VALUBusy 0.4%). Launch-overhead fusion does not pay on CDNA4
// when it requires per-block device fences.
#define BATCH   16
#define HDIM    224
#define WDIM    224
#define CDIM    64
#define HO      112
#define WO      112
#define NPATCH  (HO * WO)        // 12544 = 256 * 49
#define KSEL    1254
#define ROWF    (WDIM * CDIM)    // 14336 floats per image row
#define PERTHR  49               // keys per thread in select
#define ROWF4   (WDIM * 16)      // 3584 float4 per image row
#define BLKROW  14               // 3584 / 256 blocks per row in apply

typedef float f32x4 __attribute__((ext_vector_type(4)));

// ---------------------------------------------------------------------------
// Kernel 1: gating conv. One patch per half-wave; 2x128 contiguous floats per
// patch, float4 per lane -> wave-level 1KB contiguous loads. Memory-bound:
// 205 MB read @ ~6.3 TB/s ~ 33 us floor.
// ---------------------------------------------------------------------------
__global__ __launch_bounds__(256) void conv_gate_kernel(
    const float* __restrict__ x, const float* __restrict__ wk,
    float* __restrict__ g) {
  const int tid = threadIdx.x;
  const int lane = tid & 31;
  const int p = blockIdx.x * 8 + (tid >> 5);  // 8 half-waves/block

  const int b   = p / NPATCH;
  const int rem = p - b * NPATCH;
  const int ho  = rem / WO;
  const int wo  = rem - ho * WO;

  const float4 w0 = *reinterpret_cast<const float4*>(wk + lane * 4);
  const float4 w1 = *reinterpret_cast<const float4*>(wk + 128 + lane * 4);

  const long row0 = (long)(b * HDIM + 2 * ho) * ROWF + wo * 128 + lane * 4;
  const float4 a0 = *reinterpret_cast<const float4*>(x + row0);
  const float4 a1 = *reinterpret_cast<const float4*>(x + row0 + ROWF);

  float partial = a0.x * w0.x + a0.y * w0.y + a0.z * w0.z + a0.w * w0.w
                + a1.x * w1.x + a1.y * w1.y + a1.z * w1.z + a1.w * w1.w;

  #pragma unroll
  for (int off = 16; off > 0; off >>= 1)
    partial += __shfl_down(partial, off, 32);

  if (lane == 0) g[p] = partial;
}

// ---------------------------------------------------------------------------
// Kernel 2: exact per-batch top-K via 32-step bitwise binary search on
// order-preserving uint32 keys in registers (49/thread, 256 threads).
// One barrier per count round (double-buffered wave counts, redundant
// uniform sum). Stable lowest-index tie handling.
// ---------------------------------------------------------------------------
__global__ __launch_bounds__(256) void select_kernel(
    const float* __restrict__ g, float* __restrict__ gate) {
  __shared__ int cnt[2][4];
  __shared__ int eq_list[256];
  __shared__ int eq_count;

  const int b = blockIdx.x;
  const int tid = threadIdx.x;
  const float* __restrict__ gb  = g    + b * NPATCH;
  float* __restrict__       gtb = gate + b * NPATCH;

  uint32_t key[PERTHR];
  #pragma unroll
  for (int j = 0; j < PERTHR; ++j) {
    uint32_t u = __float_as_uint(gb[tid + j * 256]);
    key[j] = (u & 0x80000000u) ? ~u : (u | 0x80000000u);  // monotone map
  }
  if (tid == 0) eq_count = 0;

  int par = 0;
  auto block_count = [&](int c) -> int {   // one barrier per count
    #pragma unroll
    for (int off = 32; off > 0; off >>= 1) c += __shfl_down(c, off, 64);
    if ((tid & 63) == 0) cnt[par][tid >> 6] = c;
    __syncthreads();
    const int tot = cnt[par][0] + cnt[par][1] + cnt[par][2] + cnt[par][3];
    par ^= 1;
    return tot;
  };

  // T = max{t : count(keys >= t) >= K}, built bit by bit from the top.
  uint32_t T = 0;
  for (int bit = 31; bit >= 0; --bit) {
    const uint32_t cand = T | (1u << bit);
    int c = 0;
    #pragma unroll
    for (int j = 0; j < PERTHR; ++j) c += (key[j] >= cand) ? 1 : 0;
    if (block_count(c) >= KSEL) T = cand;   // uniform across block
  }

  int cg = 0;
  #pragma unroll
  for (int j = 0; j < PERTHR; ++j) cg += (key[j] > T) ? 1 : 0;
  const int krem = KSEL - block_count(cg);  // threshold ties to keep

  #pragma unroll
  for (int j = 0; j < PERTHR; ++j) {
    const int i = tid + j * 256;
    const uint32_t k = key[j];
    float v = 0.0f;
    if (k > T) {
      uint32_t u = (k & 0x80000000u) ? (k & 0x7FFFFFFFu) : ~k;
      v = __uint_as_float(u);
    }
    gtb[i] = v;
    if (k == T) {
      int pos = atomicAdd(&eq_count, 1);
      if (pos < 256) eq_list[pos] = i;
    }
  }
  __syncthreads();

  if (tid == 0) {
    const int ec = eq_count;
    const float tval =
        __uint_as_float((T & 0x80000000u) ? (T & 0x7FFFFFFFu) : ~T);
    if (ec <= 256) {
      for (int i = 0; i < ec; ++i) {          // sort tiny tie list by index
        int mn = i;
        for (int j = i + 1; j < ec; ++j)
          if (eq_list[j] < eq_list[mn]) mn = j;
        int t = eq_list[mn]; eq_list[mn] = eq_list[i]; eq_list[i] = t;
      }
      for (int i = 0; i < ec && i < krem; ++i)
        gtb[eq_list[i]] = tval;
    } else {
      int kept = 0;                            // pathological mass-tie path
      for (int i = 0; i < NPATCH && kept < krem; ++i) {
        uint32_t u = __float_as_uint(gb[i]);
        uint32_t k = (u & 0x80000000u) ? ~u : (u | 0x80000000u);
        if (k == T) { gtb[i] = tval; ++kept; }
      }
    }
  }
}

// ---------------------------------------------------------------------------
// Kernel 3: SPARSE apply. 90% of patches gate==0 -> write zeros without
// reading x (selected ~20 MB reads, L3-hit since x fits the 256 MB L3).
// Non-temporal stores for the write-once out stream. ~205 MB write floor.
// ---------------------------------------------------------------------------
__global__ __launch_bounds__(256) void apply_gate_kernel(
    const float* __restrict__ x, const float* __restrict__ gate,
    float* __restrict__ out) {
  const int bi = blockIdx.x;
  const int rowblk = bi % BLKROW;
  const int rowid  = bi / BLKROW;          // b*224 + h
  const int h = rowid % HDIM;
  const int b = rowid / HDIM;

  const int v4row = rowblk * 256 + threadIdx.x;
  const int w = v4row >> 4;
  const int gidx = b * NPATCH + (h >> 1) * WO + (w >> 1);

  const float gv = gate[gidx];
  const size_t v4 = (size_t)rowid * ROWF4 + v4row;

  f32x4 o = {0.0f, 0.0f, 0.0f, 0.0f};
  if (gv != 0.0f) {
    const f32x4 a = *reinterpret_cast<const f32x4*>(x + v4 * 4);
    o = a * gv;
  }
  __builtin_nontemporal_store(o, reinterpret_cast<f32x4*>(out + v4 * 4));
}

extern "C" void kernel_launch(void* const* d_in, const int* in_sizes, int n_in,
                              void* d_out, int out_size, void* d_ws, size_t ws_size,
                              hipStream_t stream) {
  const float* x  = (const float*)d_in[0];   // [16,224,224,64]
  const float* wk = (const float*)d_in[1];   // [2,2,64,1]
  float* out = (float*)d_out;

  float* g    = (float*)d_ws;                // [16, 12544]
  float* gate = g + BATCH * NPATCH;          // [16, 12544]

  conv_gate_kernel<<<(BATCH * NPATCH) / 8, 256, 0, stream>>>(x, wk, g);
  select_kernel<<<BATCH, 256, 0, stream>>>(g, gate);
  apply_gate_kernel<<<BATCH * HDIM * BLKROW, 256, 0, stream>>>(x, gate, out);
}